// Round 1
// baseline (880.364 us; speedup 1.0000x reference)
//
#include <hip/hip_runtime.h>
#include <math.h>

#define B_  16
#define T_  512
#define S_  1024
#define E_  1024
#define D_  1024

constexpr int BM = 64, BN = 64, BK = 16;

// C[M,N] = A[M,K] @ B, where B is (K,N) row-major if !BT, or (N,K) row-major if BT.
// Optional per-output-column scale by mask (CMASK). Batched via blockIdx.z strides.
template<bool BT, bool CMASK>
__global__ __launch_bounds__(256)
void gemm_f32(const float* __restrict__ A, const float* __restrict__ Bm,
              const float* __restrict__ mask, float* __restrict__ C,
              int N_dim, int K_dim,
              long long sA, long long sB, long long sC, int maskStride)
{
    const int bz = blockIdx.z;
    A  += (long long)bz * sA;
    Bm += (long long)bz * sB;
    C  += (long long)bz * sC;

    __shared__ float As[BK][BM];
    __shared__ float Bs[BK][BN];

    const int tid  = threadIdx.x;         // 0..255
    const int row0 = blockIdx.y * BM;
    const int col0 = blockIdx.x * BN;

    // A (and B-transposed) staging: 64 rows x 16 k, one float4 per thread
    const int lrow = tid >> 2;            // 0..63
    const int lk   = (tid & 3) << 2;      // 0,4,8,12
    // B NN staging: 16 k x 64 n, one float4 per thread
    const int bk = tid >> 4;              // 0..15
    const int bn = (tid & 15) << 2;       // 0..60

    const int tx = tid & 15;              // n dir (4 cols each)
    const int ty = tid >> 4;              // m dir (4 rows each)

    float acc[4][4] = {};

    const float* Aptr = A + (long long)(row0 + lrow) * K_dim + lk;
    const float* Bptr = BT ? (Bm + (long long)(col0 + lrow) * K_dim + lk)
                           : (Bm + (long long)bk * N_dim + col0 + bn);

    for (int k0 = 0; k0 < K_dim; k0 += BK) {
        float4 av = *(const float4*)(Aptr + k0);
        As[lk + 0][lrow] = av.x;
        As[lk + 1][lrow] = av.y;
        As[lk + 2][lrow] = av.z;
        As[lk + 3][lrow] = av.w;
        if (BT) {
            float4 bv = *(const float4*)(Bptr + k0);
            Bs[lk + 0][lrow] = bv.x;
            Bs[lk + 1][lrow] = bv.y;
            Bs[lk + 2][lrow] = bv.z;
            Bs[lk + 3][lrow] = bv.w;
        } else {
            float4 bv = *(const float4*)(Bptr + (long long)k0 * N_dim);
            *(float4*)&Bs[bk][bn] = bv;
        }
        __syncthreads();
        #pragma unroll
        for (int k = 0; k < BK; ++k) {
            float4 a4 = *(const float4*)&As[k][ty << 2];
            float4 b4 = *(const float4*)&Bs[k][tx << 2];
            float ar[4] = {a4.x, a4.y, a4.z, a4.w};
            float br[4] = {b4.x, b4.y, b4.z, b4.w};
            #pragma unroll
            for (int i = 0; i < 4; ++i)
                #pragma unroll
                for (int j = 0; j < 4; ++j)
                    acc[i][j] = fmaf(ar[i], br[j], acc[i][j]);
        }
        __syncthreads();
    }

    float mv[4] = {1.f, 1.f, 1.f, 1.f};
    if (CMASK) {
        #pragma unroll
        for (int j = 0; j < 4; ++j)
            mv[j] = mask[(long long)bz * maskStride + col0 + (tx << 2) + j];
    }

    #pragma unroll
    for (int i = 0; i < 4; ++i) {
        const int r = row0 + (ty << 2) + i;
        float4 o;
        o.x = acc[i][0] * mv[0];
        o.y = acc[i][1] * mv[1];
        o.z = acc[i][2] * mv[2];
        o.w = acc[i][3] * mv[3];
        *(float4*)&C[(long long)r * N_dim + col0 + (tx << 2)] = o;
    }
}

// Masked softmax over rows of length S_: x already equals energies*mask (0 at
// masked positions). m = max over ALL s (incl. zeros), e = exp(x-m)*mask,
// w = e / (sum(e) + 1e-6). One block of 256 threads per (b,t) row.
__global__ __launch_bounds__(256)
void softmax_mask(const float* __restrict__ x, const float* __restrict__ mask,
                  float* __restrict__ w)
{
    const int row = blockIdx.x;           // 0..B*T-1
    const int b   = row >> 9;             // T_=512
    const float* xr = x    + (long long)row * S_;
    const float* mr = mask + (long long)b * S_;
    float*       wr = w    + (long long)row * S_;
    const int tid = threadIdx.x;

    float4 xv = ((const float4*)xr)[tid];
    float4 mv = ((const float4*)mr)[tid];

    float lmax = fmaxf(fmaxf(xv.x, xv.y), fmaxf(xv.z, xv.w));
    #pragma unroll
    for (int off = 32; off; off >>= 1)
        lmax = fmaxf(lmax, __shfl_xor(lmax, off, 64));

    __shared__ float red[4];
    const int wave = tid >> 6, lane = tid & 63;
    if (lane == 0) red[wave] = lmax;
    __syncthreads();
    const float rmax = fmaxf(fmaxf(red[0], red[1]), fmaxf(red[2], red[3]));

    float e0 = expf(xv.x - rmax) * mv.x;
    float e1 = expf(xv.y - rmax) * mv.y;
    float e2 = expf(xv.z - rmax) * mv.z;
    float e3 = expf(xv.w - rmax) * mv.w;

    float lsum = (e0 + e1) + (e2 + e3);
    #pragma unroll
    for (int off = 32; off; off >>= 1)
        lsum += __shfl_xor(lsum, off, 64);

    __syncthreads();                      // protect red[] WAR
    if (lane == 0) red[wave] = lsum;
    __syncthreads();
    const float rsum = (red[0] + red[1]) + (red[2] + red[3]);
    const float inv = 1.0f / (rsum + 1e-6f);

    float4 o;
    o.x = e0 * inv; o.y = e1 * inv; o.z = e2 * inv; o.w = e3 * inv;
    ((float4*)wr)[tid] = o;
}

extern "C" void kernel_launch(void* const* d_in, const int* in_sizes, int n_in,
                              void* d_out, int out_size, void* d_ws, size_t ws_size,
                              hipStream_t stream)
{
    const float* hidden = (const float*)d_in[0];   // (B,T,D)
    const float* eo     = (const float*)d_in[1];   // (B,S,E)
    const float* ev     = (const float*)d_in[2];   // (B,S,D)
    const float* mask   = (const float*)d_in[3];   // (B,S)
    const float* W      = (const float*)d_in[4];   // (D,E) row-major

    float* out = (float*)d_out;
    const long long CTX = (long long)B_ * T_ * D_;      // 8388608
    float* ctx = out;               // output 0: context (B,T,D)
    float* aw  = out + CTX;         // output 1: attn_weights (B,T,S)
    float* ae  = out + 2 * CTX;     // output 2: attn_energies (B,T,S)

    // G = hidden @ W : (B*T, E). Stage in workspace if it fits; otherwise use
    // the attn_weights slice of d_out (dead until softmax writes it).
    const size_t Gbytes = (size_t)B_ * T_ * E_ * sizeof(float);  // 32 MiB
    float* G = (ws_size >= Gbytes) ? (float*)d_ws : aw;

    dim3 blk(256);

    // K1: G[m,e] = sum_d hidden[m,d] * W[d,e]   (one 8192x1024x1024 NN GEMM)
    gemm_f32<false, false><<<dim3(E_ / BN, (B_ * T_) / BM, 1), blk, 0, stream>>>(
        hidden, W, nullptr, G, E_, D_, 0, 0, 0, 0);

    // K2: ae[b,t,s] = mask[b,s] * sum_e G[b,t,e] * EO[b,s,e]   (batched NT GEMM)
    gemm_f32<true, true><<<dim3(S_ / BN, T_ / BM, B_), blk, 0, stream>>>(
        G, eo, mask, ae,
        S_, E_, (long long)T_ * E_, (long long)S_ * E_, (long long)T_ * S_, S_);

    // K3: masked softmax rows -> attn_weights
    softmax_mask<<<dim3(B_ * T_), blk, 0, stream>>>(ae, mask, aw);

    // K4: ctx[b,t,d] = sum_s aw[b,t,s] * EV[b,s,d]   (batched NN GEMM)
    gemm_f32<false, false><<<dim3(D_ / BN, T_ / BM, B_), blk, 0, stream>>>(
        aw, ev, nullptr, ctx,
        D_, S_, (long long)T_ * S_, (long long)S_ * D_, (long long)T_ * D_, 0);
}

// Round 2
// 359.417 us; speedup vs baseline: 2.4494x; 2.4494x over previous
//
#include <hip/hip_runtime.h>
#include <hip/hip_bf16.h>
#include <math.h>

#define B_  16
#define T_  512
#define S_  1024
#define E_  1024
#define D_  1024

using short8  = __attribute__((ext_vector_type(8))) short;
using ushort4v = __attribute__((ext_vector_type(4))) unsigned short;
using float4v = __attribute__((ext_vector_type(4))) float;

__device__ __forceinline__ unsigned short f2bf(float f) {
    unsigned u = __builtin_bit_cast(unsigned, f);
    u += 0x7fff + ((u >> 16) & 1);          // round-to-nearest-even
    return (unsigned short)(u >> 16);
}

// ---------------------------------------------------------------------------
// Transpose+cast: src (R x C) fp32 row-major -> dst (C x R) bf16 row-major.
// Batched via blockIdx.z. 64x64 tiles through LDS ([64][65] shorts: 2-way max).
// ---------------------------------------------------------------------------
__global__ __launch_bounds__(256)
void transpose_cast(const float* __restrict__ src, unsigned short* __restrict__ dst,
                    int R, int C, long long sSrc, long long sDst)
{
    __shared__ unsigned short tile[64][65];
    const int z = blockIdx.z;
    src += (long long)z * sSrc;
    dst += (long long)z * sDst;
    const int c0 = blockIdx.x * 64;
    const int r0 = blockIdx.y * 64;
    const int t = threadIdx.x;

    #pragma unroll
    for (int it = 0; it < 4; ++it) {
        int r  = (t >> 4) + it * 16;
        int c4 = (t & 15) << 2;
        float4 v = *(const float4*)&src[(long long)(r0 + r) * C + c0 + c4];
        tile[r][c4 + 0] = f2bf(v.x);
        tile[r][c4 + 1] = f2bf(v.y);
        tile[r][c4 + 2] = f2bf(v.z);
        tile[r][c4 + 3] = f2bf(v.w);
    }
    __syncthreads();
    #pragma unroll
    for (int it = 0; it < 2; ++it) {
        int c  = (t >> 3) + it * 32;
        int r8 = (t & 7) << 3;
        short8 sv;
        #pragma unroll
        for (int j = 0; j < 8; ++j) sv[j] = (short)tile[r8 + j][c];
        *(short8*)&dst[(long long)(c0 + c) * R + r0 + r8] = sv;
    }
}

// ---------------------------------------------------------------------------
// Unified MFMA GEMM: C[M,N] = A[M,K] @ B^T where both A and B are [rows][K]
// row-major (B given as [N][K]). lda = ldb = K. fp32 sources are converted to
// bf16 during LDS staging. 128x128 tile, BK=32, 4 waves, 4x4 16x16x32 frags.
// ---------------------------------------------------------------------------
template<bool A_F32, bool B_F32, bool OUT_BF16, bool CMASK>
__global__ __launch_bounds__(256)
void mfma_gemm(const void* __restrict__ Ap, const void* __restrict__ Bp,
               const float* __restrict__ mask, void* __restrict__ Cp,
               int N, int K,
               long long sA, long long sB, long long sC, int maskStride)
{
    __shared__ unsigned short Asl[128 * 40];   // rows padded to 40 shorts (80B)
    __shared__ unsigned short Bsl[128 * 40];

    const int z    = blockIdx.z;
    const int col0 = blockIdx.x * 128;
    const int row0 = blockIdx.y * 128;
    const int t    = threadIdx.x;

    const float*          Af32 = A_F32 ? ((const float*)Ap + z * sA + (long long)row0 * K) : nullptr;
    const unsigned short* Abf  = A_F32 ? nullptr : ((const unsigned short*)Ap + z * sA + (long long)row0 * K);
    const float*          Bf32 = B_F32 ? ((const float*)Bp + z * sB + (long long)col0 * K) : nullptr;
    const unsigned short* Bbf  = B_F32 ? nullptr : ((const unsigned short*)Bp + z * sB + (long long)col0 * K);

    const int lane = t & 63;
    const int wave = t >> 6;
    const int wm = (wave >> 1) * 64;
    const int wn = (wave & 1) * 64;
    const int fr = lane & 15;        // fragment row
    const int fg = lane >> 4;        // k-group (8 bf16 each)

    float4v acc[4][4];
    #pragma unroll
    for (int i = 0; i < 4; ++i)
        #pragma unroll
        for (int j = 0; j < 4; ++j)
            acc[i][j] = (float4v)0.0f;

    for (int k0 = 0; k0 < K; k0 += 32) {
        // ---- stage A ----
        if (A_F32) {
            #pragma unroll
            for (int it = 0; it < 4; ++it) {
                int r  = (t >> 3) + it * 32;
                int k4 = (t & 7) << 2;
                float4 v = *(const float4*)&Af32[(long long)r * K + k0 + k4];
                ushort4v u; u[0] = f2bf(v.x); u[1] = f2bf(v.y); u[2] = f2bf(v.z); u[3] = f2bf(v.w);
                *(ushort4v*)&Asl[r * 40 + k4] = u;
            }
        } else {
            #pragma unroll
            for (int it = 0; it < 2; ++it) {
                int r  = (t >> 2) + it * 64;
                int k8 = (t & 3) << 3;
                short8 v = *(const short8*)&Abf[(long long)r * K + k0 + k8];
                *(short8*)&Asl[r * 40 + k8] = v;
            }
        }
        // ---- stage B ----
        if (B_F32) {
            #pragma unroll
            for (int it = 0; it < 4; ++it) {
                int r  = (t >> 3) + it * 32;
                int k4 = (t & 7) << 2;
                float4 v = *(const float4*)&Bf32[(long long)r * K + k0 + k4];
                ushort4v u; u[0] = f2bf(v.x); u[1] = f2bf(v.y); u[2] = f2bf(v.z); u[3] = f2bf(v.w);
                *(ushort4v*)&Bsl[r * 40 + k4] = u;
            }
        } else {
            #pragma unroll
            for (int it = 0; it < 2; ++it) {
                int r  = (t >> 2) + it * 64;
                int k8 = (t & 3) << 3;
                short8 v = *(const short8*)&Bbf[(long long)r * K + k0 + k8];
                *(short8*)&Bsl[r * 40 + k8] = v;
            }
        }
        __syncthreads();

        short8 af[4], bf[4];
        #pragma unroll
        for (int mi = 0; mi < 4; ++mi)
            af[mi] = *(const short8*)&Asl[(wm + mi * 16 + fr) * 40 + fg * 8];
        #pragma unroll
        for (int ni = 0; ni < 4; ++ni)
            bf[ni] = *(const short8*)&Bsl[(wn + ni * 16 + fr) * 40 + fg * 8];
        #pragma unroll
        for (int mi = 0; mi < 4; ++mi)
            #pragma unroll
            for (int ni = 0; ni < 4; ++ni)
                acc[mi][ni] = __builtin_amdgcn_mfma_f32_16x16x32_bf16(af[mi], bf[ni], acc[mi][ni], 0, 0, 0);
        __syncthreads();
    }

    // ---- epilogue ----
    float mv[4];
    #pragma unroll
    for (int ni = 0; ni < 4; ++ni) {
        int ocol = col0 + wn + ni * 16 + fr;
        mv[ni] = CMASK ? mask[(long long)z * maskStride + ocol] : 1.0f;
    }
    #pragma unroll
    for (int mi = 0; mi < 4; ++mi) {
        #pragma unroll
        for (int ni = 0; ni < 4; ++ni) {
            int ocol = col0 + wn + ni * 16 + fr;
            #pragma unroll
            for (int r = 0; r < 4; ++r) {
                int orow = row0 + wm + mi * 16 + fg * 4 + r;
                float v = acc[mi][ni][r] * mv[ni];
                if (OUT_BF16)
                    ((unsigned short*)Cp)[z * sC + (long long)orow * N + ocol] = f2bf(v);
                else
                    ((float*)Cp)[z * sC + (long long)orow * N + ocol] = v;
            }
        }
    }
}

// ---------------------------------------------------------------------------
// Masked softmax (row-1 validated): x = energies*mask (0 at masked), m = max
// over ALL s, e = exp(x-m)*mask, w = e/(sum+1e-6). One 256-block per row.
// ---------------------------------------------------------------------------
__global__ __launch_bounds__(256)
void softmax_mask(const float* __restrict__ x, const float* __restrict__ mask,
                  float* __restrict__ w)
{
    const int row = blockIdx.x;
    const int b   = row >> 9;             // T_=512
    const float* xr = x    + (long long)row * S_;
    const float* mr = mask + (long long)b * S_;
    float*       wr = w    + (long long)row * S_;
    const int tid = threadIdx.x;

    float4 xv = ((const float4*)xr)[tid];
    float4 mv = ((const float4*)mr)[tid];

    float lmax = fmaxf(fmaxf(xv.x, xv.y), fmaxf(xv.z, xv.w));
    #pragma unroll
    for (int off = 32; off; off >>= 1)
        lmax = fmaxf(lmax, __shfl_xor(lmax, off, 64));

    __shared__ float red[4];
    const int wave = tid >> 6, lane = tid & 63;
    if (lane == 0) red[wave] = lmax;
    __syncthreads();
    const float rmax = fmaxf(fmaxf(red[0], red[1]), fmaxf(red[2], red[3]));

    float e0 = expf(xv.x - rmax) * mv.x;
    float e1 = expf(xv.y - rmax) * mv.y;
    float e2 = expf(xv.z - rmax) * mv.z;
    float e3 = expf(xv.w - rmax) * mv.w;

    float lsum = (e0 + e1) + (e2 + e3);
    #pragma unroll
    for (int off = 32; off; off >>= 1)
        lsum += __shfl_xor(lsum, off, 64);

    __syncthreads();
    if (lane == 0) red[wave] = lsum;
    __syncthreads();
    const float rsum = (red[0] + red[1]) + (red[2] + red[3]);
    const float inv = 1.0f / (rsum + 1e-6f);

    float4 o;
    o.x = e0 * inv; o.y = e1 * inv; o.z = e2 * inv; o.w = e3 * inv;
    ((float4*)wr)[tid] = o;
}

// ---------------------------------------------------------------------------
// Fallback fp32 GEMM (round-1 validated) — used only if d_ws is too small.
// ---------------------------------------------------------------------------
constexpr int FBM = 64, FBN = 64, FBK = 16;
template<bool BT, bool CMASK>
__global__ __launch_bounds__(256)
void gemm_f32(const float* __restrict__ A, const float* __restrict__ Bm,
              const float* __restrict__ mask, float* __restrict__ C,
              int N_dim, int K_dim,
              long long sA, long long sB, long long sC, int maskStride)
{
    const int bz = blockIdx.z;
    A  += (long long)bz * sA;
    Bm += (long long)bz * sB;
    C  += (long long)bz * sC;
    __shared__ float As[FBK][FBM];
    __shared__ float Bs[FBK][FBN];
    const int tid  = threadIdx.x;
    const int row0 = blockIdx.y * FBM;
    const int col0 = blockIdx.x * FBN;
    const int lrow = tid >> 2;
    const int lk   = (tid & 3) << 2;
    const int bk = tid >> 4;
    const int bn = (tid & 15) << 2;
    const int tx = tid & 15;
    const int ty = tid >> 4;
    float acc[4][4] = {};
    const float* Aptr = A + (long long)(row0 + lrow) * K_dim + lk;
    const float* Bptr = BT ? (Bm + (long long)(col0 + lrow) * K_dim + lk)
                           : (Bm + (long long)bk * N_dim + col0 + bn);
    for (int k0 = 0; k0 < K_dim; k0 += FBK) {
        float4 av = *(const float4*)(Aptr + k0);
        As[lk + 0][lrow] = av.x; As[lk + 1][lrow] = av.y;
        As[lk + 2][lrow] = av.z; As[lk + 3][lrow] = av.w;
        if (BT) {
            float4 bv = *(const float4*)(Bptr + k0);
            Bs[lk + 0][lrow] = bv.x; Bs[lk + 1][lrow] = bv.y;
            Bs[lk + 2][lrow] = bv.z; Bs[lk + 3][lrow] = bv.w;
        } else {
            float4 bv = *(const float4*)(Bptr + (long long)k0 * N_dim);
            *(float4*)&Bs[bk][bn] = bv;
        }
        __syncthreads();
        #pragma unroll
        for (int k = 0; k < FBK; ++k) {
            float4 a4 = *(const float4*)&As[k][ty << 2];
            float4 b4 = *(const float4*)&Bs[k][tx << 2];
            float ar[4] = {a4.x, a4.y, a4.z, a4.w};
            float br[4] = {b4.x, b4.y, b4.z, b4.w};
            #pragma unroll
            for (int i = 0; i < 4; ++i)
                #pragma unroll
                for (int j = 0; j < 4; ++j)
                    acc[i][j] = fmaf(ar[i], br[j], acc[i][j]);
        }
        __syncthreads();
    }
    float mvv[4] = {1.f, 1.f, 1.f, 1.f};
    if (CMASK) {
        #pragma unroll
        for (int j = 0; j < 4; ++j)
            mvv[j] = mask[(long long)bz * maskStride + col0 + (tx << 2) + j];
    }
    #pragma unroll
    for (int i = 0; i < 4; ++i) {
        const int r = row0 + (ty << 2) + i;
        float4 o;
        o.x = acc[i][0] * mvv[0]; o.y = acc[i][1] * mvv[1];
        o.z = acc[i][2] * mvv[2]; o.w = acc[i][3] * mvv[3];
        *(float4*)&C[(long long)r * N_dim + col0 + (tx << 2)] = o;
    }
}

extern "C" void kernel_launch(void* const* d_in, const int* in_sizes, int n_in,
                              void* d_out, int out_size, void* d_ws, size_t ws_size,
                              hipStream_t stream)
{
    const float* hidden = (const float*)d_in[0];   // (B,T,D)
    const float* eo     = (const float*)d_in[1];   // (B,S,E)
    const float* ev     = (const float*)d_in[2];   // (B,S,D)
    const float* mask   = (const float*)d_in[3];   // (B,S)
    const float* W      = (const float*)d_in[4];   // (D,E)

    float* out = (float*)d_out;
    const long long CTX = (long long)B_ * T_ * D_;
    float* ctx = out;
    float* aw  = out + CTX;
    float* ae  = out + 2 * CTX;

    const size_t WT_BYTES  = (size_t)E_ * D_ * 2;            // 2 MiB
    const size_t EVT_BYTES = (size_t)B_ * D_ * S_ * 2;       // 32 MiB
    const size_t G_BYTES   = (size_t)B_ * T_ * E_ * 2;       // 16 MiB
    const size_t NEED = WT_BYTES + EVT_BYTES + G_BYTES;

    dim3 blk(256);

    if (ws_size >= NEED) {
        unsigned short* WT  = (unsigned short*)d_ws;                       // (E, D)
        unsigned short* EVT = (unsigned short*)((char*)d_ws + WT_BYTES);   // (B, D, S)
        unsigned short* G   = (unsigned short*)((char*)d_ws + WT_BYTES + EVT_BYTES); // (B*T, E)

        // Wt[e][d] = W[d][e]
        transpose_cast<<<dim3(E_ / 64, D_ / 64, 1), blk, 0, stream>>>(
            W, WT, D_, E_, 0, 0);
        // EVt[b][d][s] = EV[b][s][d]
        transpose_cast<<<dim3(D_ / 64, S_ / 64, B_), blk, 0, stream>>>(
            ev, EVT, S_, D_, (long long)S_ * D_, (long long)D_ * S_);

        // K1: G = hidden @ W  (A fp32, B=WT bf16, out bf16)
        mfma_gemm<true, false, true, false><<<dim3(E_ / 128, (B_ * T_) / 128, 1), blk, 0, stream>>>(
            hidden, WT, nullptr, G, E_, D_, 0, 0, 0, 0);

        // K2: ae[b,t,s] = mask[b,s] * (G[b,t,:] . EO[b,s,:])  (A bf16, B fp32)
        mfma_gemm<false, true, false, true><<<dim3(S_ / 128, T_ / 128, B_), blk, 0, stream>>>(
            G, eo, mask, ae, S_, E_,
            (long long)T_ * E_, (long long)S_ * E_, (long long)T_ * S_, S_);

        // K3: softmax
        softmax_mask<<<dim3(B_ * T_), blk, 0, stream>>>(ae, mask, aw);

        // K4: ctx = aw @ EV  (A fp32, B=EVT bf16)
        mfma_gemm<true, false, false, false><<<dim3(D_ / 128, T_ / 128, B_), blk, 0, stream>>>(
            aw, EVT, nullptr, ctx, D_, S_,
            (long long)T_ * S_, (long long)D_ * S_, (long long)T_ * D_, 0);
    } else {
        // fallback: round-1 fp32 path (G fp32 staged in the aw slice)
        float* G = aw;
        gemm_f32<false, false><<<dim3(E_ / FBN, (B_ * T_) / FBM, 1), blk, 0, stream>>>(
            hidden, W, nullptr, G, E_, D_, 0, 0, 0, 0);
        gemm_f32<true, true><<<dim3(S_ / FBN, T_ / FBM, B_), blk, 0, stream>>>(
            G, eo, mask, ae, S_, E_,
            (long long)T_ * E_, (long long)S_ * E_, (long long)T_ * S_, S_);
        softmax_mask<<<dim3(B_ * T_), blk, 0, stream>>>(ae, mask, aw);
        gemm_f32<false, false><<<dim3(D_ / FBN, T_ / FBM, B_), blk, 0, stream>>>(
            aw, ev, nullptr, ctx, D_, S_,
            (long long)T_ * S_, (long long)S_ * D_, (long long)T_ * D_, 0);
    }
}

// Round 3
// 340.049 us; speedup vs baseline: 2.5889x; 1.0570x over previous
//
#include <hip/hip_runtime.h>
#include <math.h>

#define B_  16
#define T_  512
#define S_  1024
#define E_  1024
#define D_  1024

using short8   = __attribute__((ext_vector_type(8))) short;
using ushort4v = __attribute__((ext_vector_type(4))) unsigned short;
using float4v  = __attribute__((ext_vector_type(4))) float;

__device__ __forceinline__ unsigned short f2bf(float f) {
    unsigned u = __builtin_bit_cast(unsigned, f);
    u += 0x7fff + ((u >> 16) & 1);          // round-to-nearest-even
    return (unsigned short)(u >> 16);
}

__device__ __forceinline__ void gl_lds16(const void* g, void* l) {
    __builtin_amdgcn_global_load_lds(
        (const __attribute__((address_space(1))) void*)g,
        (__attribute__((address_space(3))) void*)l, 16, 0, 0);
}

// ---------------------------------------------------------------------------
// Elementwise fp32 -> bf16 cast, 8 elements/thread.
// ---------------------------------------------------------------------------
__global__ __launch_bounds__(256)
void cast_bf16(const float* __restrict__ src, unsigned short* __restrict__ dst, int n8)
{
    int i = blockIdx.x * 256 + threadIdx.x;
    if (i < n8) {
        float4 a = ((const float4*)src)[2 * i];
        float4 b = ((const float4*)src)[2 * i + 1];
        short8 o;
        o[0] = f2bf(a.x); o[1] = f2bf(a.y); o[2] = f2bf(a.z); o[3] = f2bf(a.w);
        o[4] = f2bf(b.x); o[5] = f2bf(b.y); o[6] = f2bf(b.z); o[7] = f2bf(b.w);
        ((short8*)dst)[i] = o;
    }
}

// ---------------------------------------------------------------------------
// Transpose+cast: src (R x C) fp32 row-major -> dst (C x R) bf16 row-major.
// ---------------------------------------------------------------------------
__global__ __launch_bounds__(256)
void transpose_cast(const float* __restrict__ src, unsigned short* __restrict__ dst,
                    int R, int C, long long sSrc, long long sDst)
{
    __shared__ unsigned short tile[64][65];
    const int z = blockIdx.z;
    src += (long long)z * sSrc;
    dst += (long long)z * sDst;
    const int c0 = blockIdx.x * 64;
    const int r0 = blockIdx.y * 64;
    const int t = threadIdx.x;

    #pragma unroll
    for (int it = 0; it < 4; ++it) {
        int r  = (t >> 4) + it * 16;
        int c4 = (t & 15) << 2;
        float4 v = *(const float4*)&src[(long long)(r0 + r) * C + c0 + c4];
        tile[r][c4 + 0] = f2bf(v.x);
        tile[r][c4 + 1] = f2bf(v.y);
        tile[r][c4 + 2] = f2bf(v.z);
        tile[r][c4 + 3] = f2bf(v.w);
    }
    __syncthreads();
    #pragma unroll
    for (int it = 0; it < 2; ++it) {
        int c  = (t >> 3) + it * 32;
        int r8 = (t & 7) << 3;
        short8 sv;
        #pragma unroll
        for (int j = 0; j < 8; ++j) sv[j] = (short)tile[r8 + j][c];
        *(short8*)&dst[(long long)(c0 + c) * R + r0 + r8] = sv;
    }
}

// ---------------------------------------------------------------------------
// Fast MFMA GEMM (m97 structure): C[M,N] = A @ B^T, A (M,K) bf16, B (N,K) bf16,
// both row-major. 128x128 tile, BK=32, global_load_lds width-16 staging into
// unpadded [128][32] LDS, ds_read_b128 fragments, 16x16x32 MFMA.
// ---------------------------------------------------------------------------
template<bool OUT_BF16, bool CMASK>
__global__ __launch_bounds__(256)
void mfma_gemm_bf(const unsigned short* __restrict__ Ap,
                  const unsigned short* __restrict__ Bp,
                  const float* __restrict__ mask, void* __restrict__ Cp,
                  int N, int K,
                  long long sA, long long sB, long long sC, int maskStride)
{
    __shared__ unsigned short Asl[128 * 32];
    __shared__ unsigned short Bsl[128 * 32];

    const int z    = blockIdx.z;
    const int col0 = blockIdx.x * 128;
    const int row0 = blockIdx.y * 128;
    const int t    = threadIdx.x;
    const int lane = t & 63;
    const int wave = t >> 6;

    const unsigned short* A  = Ap + z * sA + (long long)row0 * K;
    const unsigned short* Bm = Bp + z * sB + (long long)col0 * K;

    // staging: chunk c = it*256 + t covers tile bf16 elements [c*8, c*8+8)
    // tile row-major [128][32]: row = c>>2, k-offset = (c&3)*8.
    const int rs  = t >> 2;            // it=0 row; it=1 adds 64
    const int kcs = (t & 3) << 3;
    const unsigned ldsW = wave * 1024; // byte base for this wave (it=0); it=1 adds 4096

    const int wm = (wave >> 1) * 64;
    const int wn = (wave & 1) * 64;
    const int fr = lane & 15;
    const int fg = lane >> 4;

    float4v acc[4][4];
    #pragma unroll
    for (int i = 0; i < 4; ++i)
        #pragma unroll
        for (int j = 0; j < 4; ++j)
            acc[i][j] = (float4v)0.0f;

    for (int k0 = 0; k0 < K; k0 += 32) {
        #pragma unroll
        for (int it = 0; it < 2; ++it) {
            const int r = rs + it * 64;
            gl_lds16(A  + (long long)r * K + k0 + kcs, (char*)Asl + ldsW + it * 4096);
            gl_lds16(Bm + (long long)r * K + k0 + kcs, (char*)Bsl + ldsW + it * 4096);
        }
        __syncthreads();

        short8 af[4], bf[4];
        #pragma unroll
        for (int mi = 0; mi < 4; ++mi)
            af[mi] = *(const short8*)&Asl[(wm + mi * 16 + fr) * 32 + fg * 8];
        #pragma unroll
        for (int ni = 0; ni < 4; ++ni)
            bf[ni] = *(const short8*)&Bsl[(wn + ni * 16 + fr) * 32 + fg * 8];
        #pragma unroll
        for (int mi = 0; mi < 4; ++mi)
            #pragma unroll
            for (int ni = 0; ni < 4; ++ni)
                acc[mi][ni] = __builtin_amdgcn_mfma_f32_16x16x32_bf16(af[mi], bf[ni], acc[mi][ni], 0, 0, 0);
        __syncthreads();
    }

    float mv[4];
    #pragma unroll
    for (int ni = 0; ni < 4; ++ni) {
        int ocol = col0 + wn + ni * 16 + fr;
        mv[ni] = CMASK ? mask[(long long)z * maskStride + ocol] : 1.0f;
    }
    #pragma unroll
    for (int mi = 0; mi < 4; ++mi) {
        #pragma unroll
        for (int ni = 0; ni < 4; ++ni) {
            int ocol = col0 + wn + ni * 16 + fr;
            #pragma unroll
            for (int r = 0; r < 4; ++r) {
                int orow = row0 + wm + mi * 16 + fg * 4 + r;
                float v = acc[mi][ni][r] * mv[ni];
                if (OUT_BF16)
                    ((unsigned short*)Cp)[z * sC + (long long)orow * N + ocol] = f2bf(v);
                else
                    ((float*)Cp)[z * sC + (long long)orow * N + ocol] = v;
            }
        }
    }
}

// ---------------------------------------------------------------------------
// Round-2 MFMA GEMM with inline fp32->bf16 staging (fallback path).
// ---------------------------------------------------------------------------
template<bool A_F32, bool B_F32, bool OUT_BF16, bool CMASK>
__global__ __launch_bounds__(256)
void mfma_gemm(const void* __restrict__ Ap, const void* __restrict__ Bp,
               const float* __restrict__ mask, void* __restrict__ Cp,
               int N, int K,
               long long sA, long long sB, long long sC, int maskStride)
{
    __shared__ unsigned short Asl[128 * 40];
    __shared__ unsigned short Bsl[128 * 40];

    const int z    = blockIdx.z;
    const int col0 = blockIdx.x * 128;
    const int row0 = blockIdx.y * 128;
    const int t    = threadIdx.x;

    const float*          Af32 = A_F32 ? ((const float*)Ap + z * sA + (long long)row0 * K) : nullptr;
    const unsigned short* Abf  = A_F32 ? nullptr : ((const unsigned short*)Ap + z * sA + (long long)row0 * K);
    const float*          Bf32 = B_F32 ? ((const float*)Bp + z * sB + (long long)col0 * K) : nullptr;
    const unsigned short* Bbf  = B_F32 ? nullptr : ((const unsigned short*)Bp + z * sB + (long long)col0 * K);

    const int lane = t & 63;
    const int wave = t >> 6;
    const int wm = (wave >> 1) * 64;
    const int wn = (wave & 1) * 64;
    const int fr = lane & 15;
    const int fg = lane >> 4;

    float4v acc[4][4];
    #pragma unroll
    for (int i = 0; i < 4; ++i)
        #pragma unroll
        for (int j = 0; j < 4; ++j)
            acc[i][j] = (float4v)0.0f;

    for (int k0 = 0; k0 < K; k0 += 32) {
        if (A_F32) {
            #pragma unroll
            for (int it = 0; it < 4; ++it) {
                int r  = (t >> 3) + it * 32;
                int k4 = (t & 7) << 2;
                float4 v = *(const float4*)&Af32[(long long)r * K + k0 + k4];
                ushort4v u; u[0] = f2bf(v.x); u[1] = f2bf(v.y); u[2] = f2bf(v.z); u[3] = f2bf(v.w);
                *(ushort4v*)&Asl[r * 40 + k4] = u;
            }
        } else {
            #pragma unroll
            for (int it = 0; it < 2; ++it) {
                int r  = (t >> 2) + it * 64;
                int k8 = (t & 3) << 3;
                short8 v = *(const short8*)&Abf[(long long)r * K + k0 + k8];
                *(short8*)&Asl[r * 40 + k8] = v;
            }
        }
        if (B_F32) {
            #pragma unroll
            for (int it = 0; it < 4; ++it) {
                int r  = (t >> 3) + it * 32;
                int k4 = (t & 7) << 2;
                float4 v = *(const float4*)&Bf32[(long long)r * K + k0 + k4];
                ushort4v u; u[0] = f2bf(v.x); u[1] = f2bf(v.y); u[2] = f2bf(v.z); u[3] = f2bf(v.w);
                *(ushort4v*)&Bsl[r * 40 + k4] = u;
            }
        } else {
            #pragma unroll
            for (int it = 0; it < 2; ++it) {
                int r  = (t >> 2) + it * 64;
                int k8 = (t & 3) << 3;
                short8 v = *(const short8*)&Bbf[(long long)r * K + k0 + k8];
                *(short8*)&Bsl[r * 40 + k8] = v;
            }
        }
        __syncthreads();

        short8 af[4], bf[4];
        #pragma unroll
        for (int mi = 0; mi < 4; ++mi)
            af[mi] = *(const short8*)&Asl[(wm + mi * 16 + fr) * 40 + fg * 8];
        #pragma unroll
        for (int ni = 0; ni < 4; ++ni)
            bf[ni] = *(const short8*)&Bsl[(wn + ni * 16 + fr) * 40 + fg * 8];
        #pragma unroll
        for (int mi = 0; mi < 4; ++mi)
            #pragma unroll
            for (int ni = 0; ni < 4; ++ni)
                acc[mi][ni] = __builtin_amdgcn_mfma_f32_16x16x32_bf16(af[mi], bf[ni], acc[mi][ni], 0, 0, 0);
        __syncthreads();
    }

    float mv[4];
    #pragma unroll
    for (int ni = 0; ni < 4; ++ni) {
        int ocol = col0 + wn + ni * 16 + fr;
        mv[ni] = CMASK ? mask[(long long)z * maskStride + ocol] : 1.0f;
    }
    #pragma unroll
    for (int mi = 0; mi < 4; ++mi) {
        #pragma unroll
        for (int ni = 0; ni < 4; ++ni) {
            int ocol = col0 + wn + ni * 16 + fr;
            #pragma unroll
            for (int r = 0; r < 4; ++r) {
                int orow = row0 + wm + mi * 16 + fg * 4 + r;
                float v = acc[mi][ni][r] * mv[ni];
                if (OUT_BF16)
                    ((unsigned short*)Cp)[z * sC + (long long)orow * N + ocol] = f2bf(v);
                else
                    ((float*)Cp)[z * sC + (long long)orow * N + ocol] = v;
            }
        }
    }
}

// ---------------------------------------------------------------------------
// Masked softmax; optionally also writes a bf16 copy of the weights.
// ---------------------------------------------------------------------------
__global__ __launch_bounds__(256)
void softmax_mask(const float* __restrict__ x, const float* __restrict__ mask,
                  float* __restrict__ w, unsigned short* __restrict__ wbf)
{
    const int row = blockIdx.x;
    const int b   = row >> 9;             // T_=512
    const float* xr = x    + (long long)row * S_;
    const float* mr = mask + (long long)b * S_;
    float*       wr = w    + (long long)row * S_;
    const int tid = threadIdx.x;

    float4 xv = ((const float4*)xr)[tid];
    float4 mv = ((const float4*)mr)[tid];

    float lmax = fmaxf(fmaxf(xv.x, xv.y), fmaxf(xv.z, xv.w));
    #pragma unroll
    for (int off = 32; off; off >>= 1)
        lmax = fmaxf(lmax, __shfl_xor(lmax, off, 64));

    __shared__ float red[4];
    const int wave = tid >> 6, lane = tid & 63;
    if (lane == 0) red[wave] = lmax;
    __syncthreads();
    const float rmax = fmaxf(fmaxf(red[0], red[1]), fmaxf(red[2], red[3]));

    float e0 = expf(xv.x - rmax) * mv.x;
    float e1 = expf(xv.y - rmax) * mv.y;
    float e2 = expf(xv.z - rmax) * mv.z;
    float e3 = expf(xv.w - rmax) * mv.w;

    float lsum = (e0 + e1) + (e2 + e3);
    #pragma unroll
    for (int off = 32; off; off >>= 1)
        lsum += __shfl_xor(lsum, off, 64);

    __syncthreads();
    if (lane == 0) red[wave] = lsum;
    __syncthreads();
    const float rsum = (red[0] + red[1]) + (red[2] + red[3]);
    const float inv = 1.0f / (rsum + 1e-6f);

    float4 o;
    o.x = e0 * inv; o.y = e1 * inv; o.z = e2 * inv; o.w = e3 * inv;
    ((float4*)wr)[tid] = o;
    if (wbf) {
        ushort4v u;
        u[0] = f2bf(o.x); u[1] = f2bf(o.y); u[2] = f2bf(o.z); u[3] = f2bf(o.w);
        ((ushort4v*)(wbf + (long long)row * S_))[tid] = u;
    }
}

// ---------------------------------------------------------------------------
// fp32 fallback GEMM (round-1 validated).
// ---------------------------------------------------------------------------
constexpr int FBM = 64, FBN = 64, FBK = 16;
template<bool BT, bool CMASK>
__global__ __launch_bounds__(256)
void gemm_f32(const float* __restrict__ A, const float* __restrict__ Bm,
              const float* __restrict__ mask, float* __restrict__ C,
              int N_dim, int K_dim,
              long long sA, long long sB, long long sC, int maskStride)
{
    const int bz = blockIdx.z;
    A  += (long long)bz * sA;
    Bm += (long long)bz * sB;
    C  += (long long)bz * sC;
    __shared__ float As[FBK][FBM];
    __shared__ float Bs[FBK][FBN];
    const int tid  = threadIdx.x;
    const int row0 = blockIdx.y * FBM;
    const int col0 = blockIdx.x * FBN;
    const int lrow = tid >> 2;
    const int lk   = (tid & 3) << 2;
    const int bk = tid >> 4;
    const int bn = (tid & 15) << 2;
    const int tx = tid & 15;
    const int ty = tid >> 4;
    float acc[4][4] = {};
    const float* Aptr = A + (long long)(row0 + lrow) * K_dim + lk;
    const float* Bptr = BT ? (Bm + (long long)(col0 + lrow) * K_dim + lk)
                           : (Bm + (long long)bk * N_dim + col0 + bn);
    for (int k0 = 0; k0 < K_dim; k0 += FBK) {
        float4 av = *(const float4*)(Aptr + k0);
        As[lk + 0][lrow] = av.x; As[lk + 1][lrow] = av.y;
        As[lk + 2][lrow] = av.z; As[lk + 3][lrow] = av.w;
        if (BT) {
            float4 bv = *(const float4*)(Bptr + k0);
            Bs[lk + 0][lrow] = bv.x; Bs[lk + 1][lrow] = bv.y;
            Bs[lk + 2][lrow] = bv.z; Bs[lk + 3][lrow] = bv.w;
        } else {
            float4 bv = *(const float4*)(Bptr + (long long)k0 * N_dim);
            *(float4*)&Bs[bk][bn] = bv;
        }
        __syncthreads();
        #pragma unroll
        for (int k = 0; k < FBK; ++k) {
            float4 a4 = *(const float4*)&As[k][ty << 2];
            float4 b4 = *(const float4*)&Bs[k][tx << 2];
            float ar[4] = {a4.x, a4.y, a4.z, a4.w};
            float br[4] = {b4.x, b4.y, b4.z, b4.w};
            #pragma unroll
            for (int i = 0; i < 4; ++i)
                #pragma unroll
                for (int j = 0; j < 4; ++j)
                    acc[i][j] = fmaf(ar[i], br[j], acc[i][j]);
        }
        __syncthreads();
    }
    float mvv[4] = {1.f, 1.f, 1.f, 1.f};
    if (CMASK) {
        #pragma unroll
        for (int j = 0; j < 4; ++j)
            mvv[j] = mask[(long long)bz * maskStride + col0 + (tx << 2) + j];
    }
    #pragma unroll
    for (int i = 0; i < 4; ++i) {
        const int r = row0 + (ty << 2) + i;
        float4 o;
        o.x = acc[i][0] * mvv[0]; o.y = acc[i][1] * mvv[1];
        o.z = acc[i][2] * mvv[2]; o.w = acc[i][3] * mvv[3];
        *(float4*)&C[(long long)r * N_dim + col0 + (tx << 2)] = o;
    }
}

extern "C" void kernel_launch(void* const* d_in, const int* in_sizes, int n_in,
                              void* d_out, int out_size, void* d_ws, size_t ws_size,
                              hipStream_t stream)
{
    const float* hidden = (const float*)d_in[0];   // (B,T,D)
    const float* eo     = (const float*)d_in[1];   // (B,S,E)
    const float* ev     = (const float*)d_in[2];   // (B,S,D)
    const float* mask   = (const float*)d_in[3];   // (B,S)
    const float* W      = (const float*)d_in[4];   // (D,E)

    float* out = (float*)d_out;
    const long long CTX = (long long)B_ * T_ * D_;
    float* ctx = out;
    float* aw  = out + CTX;
    float* ae  = out + 2 * CTX;

    dim3 blk(256);

    const size_t MB = 1024ull * 1024ull;
    const size_t NEED_FAST = 64 * MB;
    const size_t NEED_MID  = 50 * MB;

    if (ws_size >= NEED_FAST) {
        // Phased workspace layout (aliasing by live range):
        //   [0,16)  Hbf   (dead after K1)   -> overwritten by EObf
        //   [16,18) WT    (dead after K1)
        //   [0,32)  EObf  (written after K1, dead after K2)
        //   [16,48) EVT   (written after K2)
        //   [48,64) G     (dead after K2)   -> AWbf (written by softmax)
        char* ws = (char*)d_ws;
        unsigned short* Hbf  = (unsigned short*)(ws);
        unsigned short* WT   = (unsigned short*)(ws + 16 * MB);
        unsigned short* EObf = (unsigned short*)(ws);
        unsigned short* EVT  = (unsigned short*)(ws + 16 * MB);
        unsigned short* G    = (unsigned short*)(ws + 48 * MB);
        unsigned short* AWbf = (unsigned short*)(ws + 48 * MB);

        // prep for K1
        cast_bf16<<<dim3((B_ * T_ * D_ / 8 + 255) / 256), blk, 0, stream>>>(
            hidden, Hbf, B_ * T_ * D_ / 8);
        transpose_cast<<<dim3(E_ / 64, D_ / 64, 1), blk, 0, stream>>>(
            W, WT, D_, E_, 0, 0);

        // K1: G = Hbf @ WT^T  -> bf16
        mfma_gemm_bf<true, false><<<dim3(E_ / 128, (B_ * T_) / 128, 1), blk, 0, stream>>>(
            Hbf, WT, nullptr, G, E_, D_, 0, 0, 0, 0);

        // prep for K2 (overwrites Hbf/WT)
        cast_bf16<<<dim3((B_ * S_ * E_ / 8 + 255) / 256), blk, 0, stream>>>(
            eo, EObf, B_ * S_ * E_ / 8);

        // K2: ae[b,t,s] = mask[b,s] * (G[b,t,:] . EObf[b,s,:])
        mfma_gemm_bf<false, true><<<dim3(S_ / 128, T_ / 128, B_), blk, 0, stream>>>(
            G, EObf, mask, ae, S_, E_,
            (long long)T_ * E_, (long long)S_ * E_, (long long)T_ * S_, S_);

        // prep for K4 (overwrites EObf tail; EVt[b][d][s] = EV[b][s][d])
        transpose_cast<<<dim3(D_ / 64, S_ / 64, B_), blk, 0, stream>>>(
            ev, EVT, S_, D_, (long long)S_ * D_, (long long)D_ * S_);

        // K3: softmax -> aw (fp32 out) + AWbf (bf16, aliases G)
        softmax_mask<<<dim3(B_ * T_), blk, 0, stream>>>(ae, mask, aw, AWbf);

        // K4: ctx = AWbf @ EVT^T
        mfma_gemm_bf<false, false><<<dim3(D_ / 128, T_ / 128, B_), blk, 0, stream>>>(
            AWbf, EVT, nullptr, ctx, D_, S_,
            (long long)T_ * S_, (long long)D_ * S_, (long long)T_ * D_, 0);
    } else if (ws_size >= NEED_MID) {
        unsigned short* WT  = (unsigned short*)d_ws;
        unsigned short* EVT = (unsigned short*)((char*)d_ws + 2 * MB);
        unsigned short* G   = (unsigned short*)((char*)d_ws + 34 * MB);

        transpose_cast<<<dim3(E_ / 64, D_ / 64, 1), blk, 0, stream>>>(
            W, WT, D_, E_, 0, 0);
        transpose_cast<<<dim3(D_ / 64, S_ / 64, B_), blk, 0, stream>>>(
            ev, EVT, S_, D_, (long long)S_ * D_, (long long)D_ * S_);
        mfma_gemm<true, false, true, false><<<dim3(E_ / 128, (B_ * T_) / 128, 1), blk, 0, stream>>>(
            hidden, WT, nullptr, G, E_, D_, 0, 0, 0, 0);
        mfma_gemm<false, true, false, true><<<dim3(S_ / 128, T_ / 128, B_), blk, 0, stream>>>(
            G, eo, mask, ae, S_, E_,
            (long long)T_ * E_, (long long)S_ * E_, (long long)T_ * S_, S_);
        softmax_mask<<<dim3(B_ * T_), blk, 0, stream>>>(ae, mask, aw, nullptr);
        mfma_gemm<true, false, false, false><<<dim3(D_ / 128, T_ / 128, B_), blk, 0, stream>>>(
            aw, EVT, nullptr, ctx, D_, S_,
            (long long)T_ * S_, (long long)D_ * S_, (long long)T_ * D_, 0);
    } else {
        float* G = aw;
        gemm_f32<false, false><<<dim3(E_ / FBN, (B_ * T_) / FBM, 1), blk, 0, stream>>>(
            hidden, W, nullptr, G, E_, D_, 0, 0, 0, 0);
        gemm_f32<true, true><<<dim3(S_ / FBN, T_ / FBM, B_), blk, 0, stream>>>(
            G, eo, mask, ae, S_, E_,
            (long long)T_ * E_, (long long)S_ * E_, (long long)T_ * S_, S_);
        softmax_mask<<<dim3(B_ * T_), blk, 0, stream>>>(ae, mask, aw, nullptr);
        gemm_f32<false, false><<<dim3(D_ / FBN, T_ / FBM, B_), blk, 0, stream>>>(
            aw, ev, nullptr, ctx, D_, S_,
            (long long)T_ * S_, (long long)S_ * D_, (long long)T_ * D_, 0);
    }
}

// Round 4
// 319.029 us; speedup vs baseline: 2.7595x; 1.0659x over previous
//
#include <hip/hip_runtime.h>
#include <math.h>

#define B_  16
#define T_  512
#define S_  1024
#define E_  1024
#define D_  1024

using short8   = __attribute__((ext_vector_type(8))) short;
using ushort4v = __attribute__((ext_vector_type(4))) unsigned short;
using float4v  = __attribute__((ext_vector_type(4))) float;

__device__ __forceinline__ unsigned short f2bf(float f) {
    unsigned u = __builtin_bit_cast(unsigned, f);
    u += 0x7fff + ((u >> 16) & 1);          // round-to-nearest-even
    return (unsigned short)(u >> 16);
}

__device__ __forceinline__ void gl_lds16(const void* g, void* l) {
    __builtin_amdgcn_global_load_lds(
        (const __attribute__((address_space(1))) void*)g,
        (__attribute__((address_space(3))) void*)l, 16, 0, 0);
}

// ---------------------------------------------------------------------------
// Elementwise fp32 -> bf16 cast, 8 elements/thread.
// ---------------------------------------------------------------------------
__global__ __launch_bounds__(256)
void cast_bf16(const float* __restrict__ src, unsigned short* __restrict__ dst, int n8)
{
    int i = blockIdx.x * 256 + threadIdx.x;
    if (i < n8) {
        float4 a = ((const float4*)src)[2 * i];
        float4 b = ((const float4*)src)[2 * i + 1];
        short8 o;
        o[0] = f2bf(a.x); o[1] = f2bf(a.y); o[2] = f2bf(a.z); o[3] = f2bf(a.w);
        o[4] = f2bf(b.x); o[5] = f2bf(b.y); o[6] = f2bf(b.z); o[7] = f2bf(b.w);
        ((short8*)dst)[i] = o;
    }
}

// ---------------------------------------------------------------------------
// Transpose+cast: src (R x C) fp32 row-major -> dst (C x R) bf16 row-major.
// ---------------------------------------------------------------------------
__global__ __launch_bounds__(256)
void transpose_cast(const float* __restrict__ src, unsigned short* __restrict__ dst,
                    int R, int C, long long sSrc, long long sDst)
{
    __shared__ unsigned short tile[64][65];
    const int z = blockIdx.z;
    src += (long long)z * sSrc;
    dst += (long long)z * sDst;
    const int c0 = blockIdx.x * 64;
    const int r0 = blockIdx.y * 64;
    const int t = threadIdx.x;

    #pragma unroll
    for (int it = 0; it < 4; ++it) {
        int r  = (t >> 4) + it * 16;
        int c4 = (t & 15) << 2;
        float4 v = *(const float4*)&src[(long long)(r0 + r) * C + c0 + c4];
        tile[r][c4 + 0] = f2bf(v.x);
        tile[r][c4 + 1] = f2bf(v.y);
        tile[r][c4 + 2] = f2bf(v.z);
        tile[r][c4 + 3] = f2bf(v.w);
    }
    __syncthreads();
    #pragma unroll
    for (int it = 0; it < 2; ++it) {
        int c  = (t >> 3) + it * 32;
        int r8 = (t & 7) << 3;
        short8 sv;
        #pragma unroll
        for (int j = 0; j < 8; ++j) sv[j] = (short)tile[r8 + j][c];
        *(short8*)&dst[(long long)(c0 + c) * R + r0 + r8] = sv;
    }
}

// ---------------------------------------------------------------------------
// Fast MFMA GEMM: C[M,N] = A @ B^T, A (M,K) bf16, B (N,K) bf16, row-major.
// 128x128 tile, BK=64 as TWO stacked [128][32] subtiles (m97-validated lane
// mapping per subtile), global_load_lds width-16 staging, ds_read_b128 frags,
// 16x16x32 MFMA. One barrier pair per 64-k (half of round-3's).
// ---------------------------------------------------------------------------
template<bool OUT_BF16, bool CMASK>
__global__ __launch_bounds__(256, 2)
void mfma_gemm_bf(const unsigned short* __restrict__ Ap,
                  const unsigned short* __restrict__ Bp,
                  const float* __restrict__ mask, void* __restrict__ Cp,
                  int N, int K,
                  long long sA, long long sB, long long sC, int maskStride)
{
    __shared__ unsigned short Asl[2 * 128 * 32];   // subtile j at j*4096 elems
    __shared__ unsigned short Bsl[2 * 128 * 32];

    const int z    = blockIdx.z;
    const int col0 = blockIdx.x * 128;
    const int row0 = blockIdx.y * 128;
    const int t    = threadIdx.x;
    const int lane = t & 63;
    const int wave = t >> 6;

    const unsigned short* A  = Ap + z * sA + (long long)row0 * K;
    const unsigned short* Bm = Bp + z * sB + (long long)col0 * K;

    // per-subtile staging (identical to round 3): chunk c = it*256 + t covers
    // row = c>>2, k-offset (c&3)*8 of a [128][32] subtile. LDS dest =
    // wave-uniform base (j*8192 + it*4096 + wave*1024) + lane*16.
    const int rs  = t >> 2;
    const int kcs = (t & 3) << 3;
    const unsigned ldsW = wave * 1024;

    const int wm = (wave >> 1) * 64;
    const int wn = (wave & 1) * 64;
    const int fr = lane & 15;
    const int fg = lane >> 4;

    float4v acc[4][4];
    #pragma unroll
    for (int i = 0; i < 4; ++i)
        #pragma unroll
        for (int j = 0; j < 4; ++j)
            acc[i][j] = (float4v)0.0f;

    for (int k0 = 0; k0 < K; k0 += 64) {
        #pragma unroll
        for (int j = 0; j < 2; ++j) {
            #pragma unroll
            for (int it = 0; it < 2; ++it) {
                const int r = rs + it * 64;
                const long long goff = (long long)r * K + k0 + j * 32 + kcs;
                const unsigned loff = j * 8192 + it * 4096 + ldsW;
                gl_lds16(A  + goff, (char*)Asl + loff);
                gl_lds16(Bm + goff, (char*)Bsl + loff);
            }
        }
        __syncthreads();

        short8 af[2][4], bf[2][4];
        #pragma unroll
        for (int j = 0; j < 2; ++j) {
            #pragma unroll
            for (int mi = 0; mi < 4; ++mi)
                af[j][mi] = *(const short8*)&Asl[j * 4096 + (wm + mi * 16 + fr) * 32 + fg * 8];
            #pragma unroll
            for (int ni = 0; ni < 4; ++ni)
                bf[j][ni] = *(const short8*)&Bsl[j * 4096 + (wn + ni * 16 + fr) * 32 + fg * 8];
        }
        #pragma unroll
        for (int j = 0; j < 2; ++j)
            #pragma unroll
            for (int mi = 0; mi < 4; ++mi)
                #pragma unroll
                for (int ni = 0; ni < 4; ++ni)
                    acc[mi][ni] = __builtin_amdgcn_mfma_f32_16x16x32_bf16(af[j][mi], bf[j][ni], acc[mi][ni], 0, 0, 0);
        __syncthreads();
    }

    float mv[4];
    #pragma unroll
    for (int ni = 0; ni < 4; ++ni) {
        int ocol = col0 + wn + ni * 16 + fr;
        mv[ni] = CMASK ? mask[(long long)z * maskStride + ocol] : 1.0f;
    }
    #pragma unroll
    for (int mi = 0; mi < 4; ++mi) {
        #pragma unroll
        for (int ni = 0; ni < 4; ++ni) {
            int ocol = col0 + wn + ni * 16 + fr;
            #pragma unroll
            for (int r = 0; r < 4; ++r) {
                int orow = row0 + wm + mi * 16 + fg * 4 + r;
                float v = acc[mi][ni][r] * mv[ni];
                if (OUT_BF16)
                    ((unsigned short*)Cp)[z * sC + (long long)orow * N + ocol] = f2bf(v);
                else
                    ((float*)Cp)[z * sC + (long long)orow * N + ocol] = v;
            }
        }
    }
}

// ---------------------------------------------------------------------------
// Masked softmax; also writes a bf16 copy of the weights when wbf != nullptr.
// ---------------------------------------------------------------------------
__global__ __launch_bounds__(256)
void softmax_mask(const float* __restrict__ x, const float* __restrict__ mask,
                  float* __restrict__ w, unsigned short* __restrict__ wbf)
{
    const int row = blockIdx.x;
    const int b   = row >> 9;             // T_=512
    const float* xr = x    + (long long)row * S_;
    const float* mr = mask + (long long)b * S_;
    float*       wr = w    + (long long)row * S_;
    const int tid = threadIdx.x;

    float4 xv = ((const float4*)xr)[tid];
    float4 mv = ((const float4*)mr)[tid];

    float lmax = fmaxf(fmaxf(xv.x, xv.y), fmaxf(xv.z, xv.w));
    #pragma unroll
    for (int off = 32; off; off >>= 1)
        lmax = fmaxf(lmax, __shfl_xor(lmax, off, 64));

    __shared__ float red[4];
    const int wave = tid >> 6, lane = tid & 63;
    if (lane == 0) red[wave] = lmax;
    __syncthreads();
    const float rmax = fmaxf(fmaxf(red[0], red[1]), fmaxf(red[2], red[3]));

    float e0 = expf(xv.x - rmax) * mv.x;
    float e1 = expf(xv.y - rmax) * mv.y;
    float e2 = expf(xv.z - rmax) * mv.z;
    float e3 = expf(xv.w - rmax) * mv.w;

    float lsum = (e0 + e1) + (e2 + e3);
    #pragma unroll
    for (int off = 32; off; off >>= 1)
        lsum += __shfl_xor(lsum, off, 64);

    __syncthreads();
    if (lane == 0) red[wave] = lsum;
    __syncthreads();
    const float rsum = (red[0] + red[1]) + (red[2] + red[3]);
    const float inv = 1.0f / (rsum + 1e-6f);

    float4 o;
    o.x = e0 * inv; o.y = e1 * inv; o.z = e2 * inv; o.w = e3 * inv;
    ((float4*)wr)[tid] = o;
    if (wbf) {
        ushort4v u;
        u[0] = f2bf(o.x); u[1] = f2bf(o.y); u[2] = f2bf(o.z); u[3] = f2bf(o.w);
        ((ushort4v*)(wbf + (long long)row * S_))[tid] = u;
    }
}

// ---------------------------------------------------------------------------
// fp32 fallback GEMM (round-1 validated) — used only if d_ws is tiny.
// ---------------------------------------------------------------------------
constexpr int FBM = 64, FBN = 64, FBK = 16;
template<bool BT, bool CMASK>
__global__ __launch_bounds__(256)
void gemm_f32(const float* __restrict__ A, const float* __restrict__ Bm,
              const float* __restrict__ mask, float* __restrict__ C,
              int N_dim, int K_dim,
              long long sA, long long sB, long long sC, int maskStride)
{
    const int bz = blockIdx.z;
    A  += (long long)bz * sA;
    Bm += (long long)bz * sB;
    C  += (long long)bz * sC;
    __shared__ float As[FBK][FBM];
    __shared__ float Bs[FBK][FBN];
    const int tid  = threadIdx.x;
    const int row0 = blockIdx.y * FBM;
    const int col0 = blockIdx.x * FBN;
    const int lrow = tid >> 2;
    const int lk   = (tid & 3) << 2;
    const int bk = tid >> 4;
    const int bn = (tid & 15) << 2;
    const int tx = tid & 15;
    const int ty = tid >> 4;
    float acc[4][4] = {};
    const float* Aptr = A + (long long)(row0 + lrow) * K_dim + lk;
    const float* Bptr = BT ? (Bm + (long long)(col0 + lrow) * K_dim + lk)
                           : (Bm + (long long)bk * N_dim + col0 + bn);
    for (int k0 = 0; k0 < K_dim; k0 += FBK) {
        float4 av = *(const float4*)(Aptr + k0);
        As[lk + 0][lrow] = av.x; As[lk + 1][lrow] = av.y;
        As[lk + 2][lrow] = av.z; As[lk + 3][lrow] = av.w;
        if (BT) {
            float4 bv = *(const float4*)(Bptr + k0);
            Bs[lk + 0][lrow] = bv.x; Bs[lk + 1][lrow] = bv.y;
            Bs[lk + 2][lrow] = bv.z; Bs[lk + 3][lrow] = bv.w;
        } else {
            float4 bv = *(const float4*)(Bptr + (long long)k0 * N_dim);
            *(float4*)&Bs[bk][bn] = bv;
        }
        __syncthreads();
        #pragma unroll
        for (int k = 0; k < FBK; ++k) {
            float4 a4 = *(const float4*)&As[k][ty << 2];
            float4 b4 = *(const float4*)&Bs[k][tx << 2];
            float ar[4] = {a4.x, a4.y, a4.z, a4.w};
            float br[4] = {b4.x, b4.y, b4.z, b4.w};
            #pragma unroll
            for (int i = 0; i < 4; ++i)
                #pragma unroll
                for (int j = 0; j < 4; ++j)
                    acc[i][j] = fmaf(ar[i], br[j], acc[i][j]);
        }
        __syncthreads();
    }
    float mvv[4] = {1.f, 1.f, 1.f, 1.f};
    if (CMASK) {
        #pragma unroll
        for (int j = 0; j < 4; ++j)
            mvv[j] = mask[(long long)bz * maskStride + col0 + (tx << 2) + j];
    }
    #pragma unroll
    for (int i = 0; i < 4; ++i) {
        const int r = row0 + (ty << 2) + i;
        float4 o;
        o.x = acc[i][0] * mvv[0]; o.y = acc[i][1] * mvv[1];
        o.z = acc[i][2] * mvv[2]; o.w = acc[i][3] * mvv[3];
        *(float4*)&C[(long long)r * N_dim + col0 + (tx << 2)] = o;
    }
}

extern "C" void kernel_launch(void* const* d_in, const int* in_sizes, int n_in,
                              void* d_out, int out_size, void* d_ws, size_t ws_size,
                              hipStream_t stream)
{
    const float* hidden = (const float*)d_in[0];   // (B,T,D)
    const float* eo     = (const float*)d_in[1];   // (B,S,E)
    const float* ev     = (const float*)d_in[2];   // (B,S,D)
    const float* mask   = (const float*)d_in[3];   // (B,S)
    const float* W      = (const float*)d_in[4];   // (D,E)

    float* out = (float*)d_out;
    const long long CTX = (long long)B_ * T_ * D_;
    float* ctx = out;
    float* aw  = out + CTX;
    float* ae  = out + 2 * CTX;

    dim3 blk(256);
    const size_t MB = 1024ull * 1024ull;
    const size_t NEED_FAST = 64 * MB;

    if (ws_size >= NEED_FAST) {
        // Phased workspace layout (aliasing by live range):
        //   [0,16)  Hbf  (dead after K1) -> EObf [0,32) after K1
        //   [16,18) WT   (dead after K1)
        //   [16,48) EVT  (written after K2)
        //   [48,64) G    (dead after K2) -> AWbf
        char* ws = (char*)d_ws;
        unsigned short* Hbf  = (unsigned short*)(ws);
        unsigned short* WT   = (unsigned short*)(ws + 16 * MB);
        unsigned short* EObf = (unsigned short*)(ws);
        unsigned short* EVT  = (unsigned short*)(ws + 16 * MB);
        unsigned short* G    = (unsigned short*)(ws + 48 * MB);
        unsigned short* AWbf = (unsigned short*)(ws + 48 * MB);

        cast_bf16<<<dim3((B_ * T_ * D_ / 8 + 255) / 256), blk, 0, stream>>>(
            hidden, Hbf, B_ * T_ * D_ / 8);
        transpose_cast<<<dim3(E_ / 64, D_ / 64, 1), blk, 0, stream>>>(
            W, WT, D_, E_, 0, 0);

        // K1: G = Hbf @ WT^T  -> bf16
        mfma_gemm_bf<true, false><<<dim3(E_ / 128, (B_ * T_) / 128, 1), blk, 0, stream>>>(
            Hbf, WT, nullptr, G, E_, D_, 0, 0, 0, 0);

        cast_bf16<<<dim3((B_ * S_ * E_ / 8 + 255) / 256), blk, 0, stream>>>(
            eo, EObf, B_ * S_ * E_ / 8);

        // K2: ae[b,t,s] = mask[b,s] * (G[b,t,:] . EObf[b,s,:])
        mfma_gemm_bf<false, true><<<dim3(S_ / 128, T_ / 128, B_), blk, 0, stream>>>(
            G, EObf, mask, ae, S_, E_,
            (long long)T_ * E_, (long long)S_ * E_, (long long)T_ * S_, S_);

        // EVt[b][d][s] = EV[b][s][d]
        transpose_cast<<<dim3(D_ / 64, S_ / 64, B_), blk, 0, stream>>>(
            ev, EVT, S_, D_, (long long)S_ * D_, (long long)D_ * S_);

        // K3: softmax -> aw (fp32) + AWbf (bf16, aliases G)
        softmax_mask<<<dim3(B_ * T_), blk, 0, stream>>>(ae, mask, aw, AWbf);

        // K4: ctx = AWbf @ EVT^T
        mfma_gemm_bf<false, false><<<dim3(D_ / 128, T_ / 128, B_), blk, 0, stream>>>(
            AWbf, EVT, nullptr, ctx, D_, S_,
            (long long)T_ * S_, (long long)D_ * S_, (long long)T_ * D_, 0);
    } else {
        float* G = aw;
        gemm_f32<false, false><<<dim3(E_ / FBN, (B_ * T_) / FBM, 1), blk, 0, stream>>>(
            hidden, W, nullptr, G, E_, D_, 0, 0, 0, 0);
        gemm_f32<true, true><<<dim3(S_ / FBN, T_ / FBM, B_), blk, 0, stream>>>(
            G, eo, mask, ae, S_, E_,
            (long long)T_ * E_, (long long)S_ * E_, (long long)T_ * S_, S_);
        softmax_mask<<<dim3(B_ * T_), blk, 0, stream>>>(ae, mask, aw, nullptr);
        gemm_f32<false, false><<<dim3(D_ / FBN, T_ / FBM, B_), blk, 0, stream>>>(
            aw, ev, nullptr, ctx, D_, S_,
            (long long)T_ * S_, (long long)S_ * D_, (long long)T_ * D_, 0);
    }
}